// Round 7
// baseline (13775.435 us; speedup 1.0000x reference)
//
#include <hip/hip_runtime.h>
#include <hip/hip_bf16.h>
#include <stdint.h>

// Problem dims
#define B_  32
#define T_  512
#define E_  256
#define H_  512
#define K_  17
// 4H = 2048

typedef unsigned short us;
typedef __attribute__((ext_vector_type(8))) short short8;
typedef __attribute__((ext_vector_type(4))) float f32x4;

__device__ __forceinline__ float bf2f(unsigned int u16) {
    union { unsigned int i; float f; } v; v.i = u16 << 16; return v.f;
}
__device__ __forceinline__ us f2bf(float f) {
    union { float f; unsigned int i; } v; v.f = f;
    unsigned int b = v.i;
    return (us)((b + 0x7FFFu + ((b >> 16) & 1u)) >> 16);
}
__device__ __forceinline__ float sigf(float x) { return 1.0f / (1.0f + __expf(-x)); }
__device__ __forceinline__ float tanhf_(float x) { return 1.0f - 2.0f / (__expf(2.0f * x) + 1.0f); }

// ---------------------------------------------------------------------------
// Kernel 0: float32 -> bf16 conversion (RNE), 4 elements/thread.
__global__ void k_cvt(const float* __restrict__ src, us* __restrict__ dst, int n4) {
    int i = blockIdx.x * 256 + threadIdx.x;
    if (i < n4) {
        float4 v = ((const float4*)src)[i];
        uint2 p;
        p.x = (uint32_t)f2bf(v.x) | ((uint32_t)f2bf(v.y) << 16);
        p.y = (uint32_t)f2bf(v.z) | ((uint32_t)f2bf(v.w) << 16);
        ((uint2*)dst)[i] = p;
    }
}

// ---------------------------------------------------------------------------
// Kernel 1: sentinel + marker init + gathered token-index table.
// ids2 layout: [dir][t*B + b]
__global__ void k_init(const int* __restrict__ ids, const int* __restrict__ lengths,
                       int* __restrict__ ids2, int* __restrict__ marker,
                       float* __restrict__ out) {
    int idx = blockIdx.x * 256 + threadIdx.x;
    if (idx == 0) { *marker = 1; out[0] = -3328.0f; }
    if (idx < 2 * B_ * T_) {
        int dir = idx >> 14;           // 16384 per dir
        int r   = idx & 16383;
        int t   = r >> 5;              // t-major, B=32
        int b   = r & 31;
        int l   = lengths[b];
        int tt  = (dir == 0) ? t : ((t < l) ? (l - 1 - t) : t);
        ids2[idx] = ids[b * T_ + tt];
    }
}

// ---------------------------------------------------------------------------
// Kernel 2: xg[dir][t*B+b][jg] = (emb[ids2] @ W_ih^T + bias), permuted layout
// jg = j*4 + g  (torch gates i,f,g,o contiguous per hidden index j).
// M = permuted W rows (2048), N = tokens (16384). 64x64 tiles, K staged 2x128.
__launch_bounds__(256)
__global__ void k_xg(const us* __restrict__ emb,
                     const us* __restrict__ wf, const float* __restrict__ bfv,
                     const us* __restrict__ wb, const float* __restrict__ bbv,
                     const int* __restrict__ ids2, us* __restrict__ xg,
                     int* __restrict__ marker) {
    if (blockIdx.x == 0 && blockIdx.y == 0 && blockIdx.z == 0 && threadIdx.x == 0)
        atomicOr(marker, 2);
    int mt = blockIdx.x, nt = blockIdx.y, dir = blockIdx.z;
    const us* W      = dir ? wb  : wf;
    const float* bias = dir ? bbv : bfv;
    const int* id2 = ids2 + dir * (B_ * T_);
    us* xgd = xg + (size_t)dir * B_ * T_ * 2048;
    int m0 = mt * 64, n0 = nt * 64;
    __shared__ __align__(16) us As[64][136];
    __shared__ __align__(16) us Bs[64][136];
    int tid = threadIdx.x;
    int wv = tid >> 6, lane = tid & 63;
    int lm = lane & 15, lg = lane >> 4;
    f32x4 z = {0.f, 0.f, 0.f, 0.f};
    f32x4 acc[4] = {z, z, z, z};
    for (int half = 0; half < 2; ++half) {
        for (int c = tid; c < 1024; c += 256) {
            int row = c >> 4, cb = c & 15;
            int mg = m0 + row;
            int j = mg >> 2, g = mg & 3;
            *(uint4*)&As[row][cb * 8] =
                *(const uint4*)(W + ((size_t)(g * H_ + j)) * E_ + half * 128 + cb * 8);
            int gi = id2[n0 + row];
            *(uint4*)&Bs[row][cb * 8] =
                *(const uint4*)(emb + (size_t)gi * E_ + half * 128 + cb * 8);
        }
        __syncthreads();
#pragma unroll
        for (int kt = 0; kt < 4; ++kt) {
            short8 a = *(const short8*)&As[wv * 16 + lm][kt * 32 + lg * 8];
#pragma unroll
            for (int n2 = 0; n2 < 4; ++n2) {
                short8 b = *(const short8*)&Bs[n2 * 16 + lm][kt * 32 + lg * 8];
                acc[n2] = __builtin_amdgcn_mfma_f32_16x16x32_bf16(a, b, acc[n2], 0, 0, 0);
            }
        }
        __syncthreads();
    }
    int jgb = m0 + wv * 16 + lg * 4;
    int j = jgb >> 2;
#pragma unroll
    for (int n2 = 0; n2 < 4; ++n2) {
        int token = n0 + n2 * 16 + lm;
        us p[4];
#pragma unroll
        for (int q = 0; q < 4; ++q)
            p[q] = f2bf(acc[n2][q] + bias[q * H_ + j]);
        uint2 pv;
        pv.x = (uint32_t)p[0] | ((uint32_t)p[1] << 16);
        pv.y = (uint32_t)p[2] | ((uint32_t)p[3] << 16);
        *(uint2*)(xgd + (size_t)token * 2048 + jgb) = pv;
    }
}

// ---------------------------------------------------------------------------
// Kernel 3: ONE LSTM time-step for both directions. NO cross-wg sync —
// the kernel boundary is the global barrier (512 chained launches).
// grid (8,2): wg = 256 permuted gate-rows of one dir; W streamed from L2.
// h_buf: [dir][parity][b][H] bf16; c_buf: [dir][j][b] f32 (t==0 never reads).
__launch_bounds__(256)
__global__ void k_step(const us* __restrict__ whf, const us* __restrict__ whb,
                       const us* __restrict__ xg, us* __restrict__ h_buf,
                       float* __restrict__ c_buf, us* __restrict__ h_out,
                       int t, int* __restrict__ marker) {
    int wgr = blockIdx.x;            // 0..7: rows wgr*256 .. +255
    int dir = blockIdx.y;
    int tid = threadIdx.x;
    if (t == 0 && wgr == 0 && dir == 0 && tid == 0) atomicOr(marker, 4);
    const us* W = dir ? whb : whf;
    const us* xgd = xg + (size_t)dir * B_ * T_ * 2048;
    const us* hprev = h_buf + (size_t)(dir * 2 + ((t + 1) & 1)) * (B_ * H_);
    us* hcur        = h_buf + (size_t)(dir * 2 + (t & 1)) * (B_ * H_);
    float* cb = c_buf + (size_t)dir * (H_ * B_);
    us* hod = h_out + (size_t)dir * B_ * T_ * H_;
    int wv = tid >> 6, lane = tid & 63;
    int lm = lane & 15, lg = lane >> 4;
#pragma unroll
    for (int mi = 0; mi < 4; ++mi) {
        int mrow = wgr * 256 + (wv * 4 + mi) * 16;   // permuted-row base (j*4+g)
        f32x4 acc[2];
#pragma unroll
        for (int nt = 0; nt < 2; ++nt) {             // init from xg (gates+bias)
            int b = nt * 16 + lm;
            uint2 v = *(const uint2*)(xgd + ((size_t)(t * B_ + b)) * 2048 + mrow + lg * 4);
            acc[nt][0] = bf2f(v.x & 0xffff); acc[nt][1] = bf2f(v.x >> 16);
            acc[nt][2] = bf2f(v.y & 0xffff); acc[nt][3] = bf2f(v.y >> 16);
        }
        if (t > 0) {
            int prow = mrow + lm;                    // A-frag row (M)
            int j = prow >> 2, g = prow & 3;
            const us* wrow = W + (size_t)(g * H_ + j) * H_;
#pragma unroll
            for (int kt = 0; kt < 16; ++kt) {
                short8 a  = *(const short8*)(wrow + kt * 32 + lg * 8);
                short8 b0 = *(const short8*)(hprev + (size_t)(0 * 16 + lm) * H_ + kt * 32 + lg * 8);
                short8 b1 = *(const short8*)(hprev + (size_t)(1 * 16 + lm) * H_ + kt * 32 + lg * 8);
                acc[0] = __builtin_amdgcn_mfma_f32_16x16x32_bf16(a, b0, acc[0], 0, 0, 0);
                acc[1] = __builtin_amdgcn_mfma_f32_16x16x32_bf16(a, b1, acc[1], 0, 0, 0);
            }
        }
        int jj = (mrow >> 2) + lg;                   // this lane's hidden index
#pragma unroll
        for (int nt = 0; nt < 2; ++nt) {             // gates i,f,g,o in acc[nt][0..3]
            int b = nt * 16 + lm;
            float cold = (t > 0) ? cb[jj * B_ + b] : 0.0f;
            float ci = sigf(acc[nt][1]) * cold + sigf(acc[nt][0]) * tanhf_(acc[nt][2]);
            cb[jj * B_ + b] = ci;
            float h = sigf(acc[nt][3]) * tanhf_(ci);
            us hv = f2bf(h);
            hcur[(size_t)b * H_ + jj] = hv;
            hod[((size_t)b * T_ + t) * H_ + jj] = hv;
        }
    }
}

// ---------------------------------------------------------------------------
// Kernel 4: emissions[b*T+t][k] = [hf(b,t), hb(b,rev)] . w_cls[k] + b_cls[k]
__launch_bounds__(256)
__global__ void k_emis(const us* __restrict__ h_out,
                       const us* __restrict__ wcls, const float* __restrict__ bcls,
                       const int* __restrict__ lengths, float* __restrict__ emis,
                       int* __restrict__ marker) {
    if (blockIdx.x == 0 && threadIdx.x == 0) atomicOr(marker, 8);
    __shared__ __align__(8) us Wc[17][1032];
    int tid = threadIdx.x;
    for (int c = tid; c < 17 * 256; c += 256) {
        int row = c >> 8; int c4 = (c & 255) * 4;
        *(uint2*)&Wc[row][c4] = *(const uint2*)(wcls + (size_t)row * 1024 + c4);
    }
    __syncthreads();
    int i = blockIdx.x * 8 + (tid >> 5);
    int k = tid & 31;
    int b = i >> 9, t = i & 511;
    int l = lengths[b];
    int trv = (t < l) ? (l - 1 - t) : t;
    const us* hf = h_out + ((size_t)(0 * B_ + b) * T_ + t) * H_;
    const us* hb = h_out + ((size_t)(1 * B_ + b) * T_ + trv) * H_;
    if (k < K_) {
        float acc = bcls[k];
        for (int e = 0; e < H_; e += 4) {
            uint2 hv = *(const uint2*)(hf + e);
            uint2 wv = *(const uint2*)&Wc[k][e];
            acc = fmaf(bf2f(hv.x & 0xffff), bf2f(wv.x & 0xffff), acc);
            acc = fmaf(bf2f(hv.x >> 16),    bf2f(wv.x >> 16),    acc);
            acc = fmaf(bf2f(hv.y & 0xffff), bf2f(wv.y & 0xffff), acc);
            acc = fmaf(bf2f(hv.y >> 16),    bf2f(wv.y >> 16),    acc);
        }
        for (int e = 0; e < H_; e += 4) {
            uint2 hv = *(const uint2*)(hb + e);
            uint2 wv = *(const uint2*)&Wc[k][512 + e];
            acc = fmaf(bf2f(hv.x & 0xffff), bf2f(wv.x & 0xffff), acc);
            acc = fmaf(bf2f(hv.x >> 16),    bf2f(wv.x >> 16),    acc);
            acc = fmaf(bf2f(hv.y & 0xffff), bf2f(wv.y & 0xffff), acc);
            acc = fmaf(bf2f(hv.y >> 16),    bf2f(wv.y >> 16),    acc);
        }
        emis[(size_t)i * 20 + k] = acc;
    }
}

// ---------------------------------------------------------------------------
// Kernel 5: CRF numerator + forward algorithm per batch (1 wave per batch)
__global__ void k_crf(const float* __restrict__ emis, const int* __restrict__ tags,
                      const int* __restrict__ lengths,
                      const float* __restrict__ start_t, const float* __restrict__ trans_t,
                      const float* __restrict__ end_t, float* __restrict__ res,
                      int* __restrict__ marker) {
    if (blockIdx.x == 0 && threadIdx.x == 0) atomicOr(marker, 16);
    __shared__ float tr[17][18];
    __shared__ float alpha[17];
    int b = blockIdx.x, tid = threadIdx.x;
    for (int i = tid; i < 289; i += 64) tr[i / 17][i % 17] = trans_t[i];
    __syncthreads();
    int l = lengths[b];
    const int* tg = tags + b * T_;
    const float* eb = emis + (size_t)b * T_ * 20;
    float sn = 0.f;
    for (int t = tid; t < T_; t += 64) {
        if (t < l) {
            sn += eb[t * 20 + tg[t]];
            if (t >= 1) sn += tr[tg[t - 1]][tg[t]];
        }
    }
#pragma unroll
    for (int off = 32; off; off >>= 1) sn += __shfl_xor(sn, off, 64);
    float numer = sn + start_t[tg[0]] + end_t[tg[l - 1]];
    int k = (tid < K_) ? tid : 0;
    if (tid < K_) alpha[tid] = start_t[tid] + eb[tid];
    __syncthreads();
    for (int t = 1; t < l; ++t) {
        float av[17];
        float m = -1e30f;
#pragma unroll
        for (int j = 0; j < 17; ++j) { av[j] = alpha[j] + tr[j][k]; m = fmaxf(m, av[j]); }
        float s = 0.f;
#pragma unroll
        for (int j = 0; j < 17; ++j) s += __expf(av[j] - m);
        float nxt = m + __logf(s) + eb[t * 20 + k];
        __syncthreads();
        if (tid < K_) alpha[tid] = nxt;
        __syncthreads();
    }
    float v = (tid < K_) ? (alpha[tid] + end_t[tid]) : -1e30f;
    float m2 = v;
#pragma unroll
    for (int off = 32; off; off >>= 1) m2 = fmaxf(m2, __shfl_xor(m2, off, 64));
    float s2 = __expf(v - m2);
#pragma unroll
    for (int off = 32; off; off >>= 1) s2 += __shfl_xor(s2, off, 64);
    if (tid == 0) res[b] = numer - (m2 + __logf(s2));
}

// ---------------------------------------------------------------------------
// Kernel 6 (LAST): float32 output, negative diagnostic codes:
//   hm!=0 -> -(16384+512*hm) ; dm!=31 -> -(8192+128*dm) ;
//   NaN in res[b] -> -(4096+b) ; else loss (positive ~1048).
__global__ void k_fin(const float* __restrict__ res, int* __restrict__ marker,
                      int hostmask, float* __restrict__ out) {
    int tid = threadIdx.x;
    if (hostmask != 0) {
        if (tid == 0) out[0] = -(16384.0f + 512.0f * (float)hostmask);
        return;
    }
    int dm = atomicOr(marker, 0);
    if (dm != 31) {
        if (tid == 0) out[0] = -(8192.0f + 128.0f * (float)(dm & 63));
        return;
    }
    float v = (tid < B_) ? res[tid] : 0.f;
    unsigned long long nb = __ballot(v != v);
    if (nb != 0ULL) {
        if (tid == 0) out[0] = -(4096.0f + (float)(__ffsll((long long)nb) - 1));
        return;
    }
#pragma unroll
    for (int off = 32; off; off >>= 1) v += __shfl_xor(v, off, 64);
    if (tid == 0) out[0] = -(v / (float)B_);
}

// ---------------------------------------------------------------------------
extern "C" void kernel_launch(void* const* d_in, const int* in_sizes, int n_in,
                              void* d_out, int out_size, void* d_ws, size_t ws_size,
                              hipStream_t stream) {
    const int* ids      = (const int*)d_in[0];
    const int* lengths  = (const int*)d_in[1];
    const int* tags     = (const int*)d_in[2];
    // d_in[3] = mask (recomputed from lengths)
    const float* emb_f  = (const float*)d_in[4];
    const float* wihf_f = (const float*)d_in[5];
    const float* whhf_f = (const float*)d_in[6];
    const float* bfv    = (const float*)d_in[7];
    const float* wihb_f = (const float*)d_in[8];
    const float* whhb_f = (const float*)d_in[9];
    const float* bbv    = (const float*)d_in[10];
    const float* wcls_f = (const float*)d_in[11];
    const float* bcls   = (const float*)d_in[12];
    const float* start  = (const float*)d_in[13];
    const float* trans  = (const float*)d_in[14];
    const float* endt   = (const float*)d_in[15];
    float* out = (float*)d_out;

    // host-side validation (element counts)
    int hm = 0;
    if (n_in != 16 || out_size != 1) hm |= 8;
    const int exp_sz[16] = {
        16384, 32, 16384, 16384,
        12800000,
        524288, 1048576, 2048,
        524288, 1048576, 2048,
        17408, 17,
        17, 289, 17
    };
    if (!(hm & 8))
        for (int i = 0; i < 16; ++i)
            if (in_sizes[i] != exp_sz[i]) hm |= 2;

    // workspace carve (256B aligned)
    char* w = (char*)d_ws;
    size_t off = 0;
    auto carve = [&](size_t bytes) { void* p = w + off; off += (bytes + 255) & ~(size_t)255; return p; };
    int* ids2    = (int*)carve((size_t)2 * B_ * T_ * 4);
    int* marker  = (int*)carve(256);
    float* res   = (float*)carve(256);
    float* emis  = (float*)carve((size_t)B_ * T_ * 20 * 4);
    us* xg       = (us*)carve((size_t)2 * B_ * T_ * 2048 * 2);
    us* h_buf    = (us*)carve((size_t)2 * 2 * B_ * H_ * 2);
    float* c_buf = (float*)carve((size_t)2 * H_ * B_ * 4);
    us* h_out    = (us*)carve((size_t)2 * B_ * T_ * H_ * 2);
    us* emb_b    = (us*)carve((size_t)12800000 * 2);
    us* wihf_b   = (us*)carve((size_t)524288 * 2);
    us* wihb_b   = (us*)carve((size_t)524288 * 2);
    us* whhf_b   = (us*)carve((size_t)1048576 * 2);
    us* whhb_b   = (us*)carve((size_t)1048576 * 2);
    us* wcls_b   = (us*)carve((size_t)17408 * 2);
    if (off > ws_size) hm |= 4;

    (void)hipGetLastError();
    if ((hm & (2 | 4 | 8)) == 0) {
        k_init<<<(2 * B_ * T_ + 255) / 256, 256, 0, stream>>>(ids, lengths, ids2, marker, out);
        // f32 -> bf16 conversions
        k_cvt<<<(12800000 / 4 + 255) / 256, 256, 0, stream>>>(emb_f,  emb_b,  12800000 / 4);
        k_cvt<<<(524288   / 4 + 255) / 256, 256, 0, stream>>>(wihf_f, wihf_b, 524288 / 4);
        k_cvt<<<(524288   / 4 + 255) / 256, 256, 0, stream>>>(wihb_f, wihb_b, 524288 / 4);
        k_cvt<<<(1048576  / 4 + 255) / 256, 256, 0, stream>>>(whhf_f, whhf_b, 1048576 / 4);
        k_cvt<<<(1048576  / 4 + 255) / 256, 256, 0, stream>>>(whhb_f, whhb_b, 1048576 / 4);
        k_cvt<<<(17408    / 4 + 255) / 256, 256, 0, stream>>>(wcls_f, wcls_b, 17408 / 4);
        k_xg<<<dim3(2048 / 64, B_ * T_ / 64, 2), 256, 0, stream>>>(emb_b, wihf_b, bfv, wihb_b, bbv, ids2, xg, marker);
        for (int t = 0; t < T_; ++t)
            k_step<<<dim3(8, 2), 256, 0, stream>>>(whhf_b, whhb_b, xg, h_buf, c_buf, h_out, t, marker);
        k_emis<<<B_ * T_ / 8, 256, 0, stream>>>(h_out, wcls_b, bcls, lengths, emis, marker);
        k_crf<<<B_, 64, 0, stream>>>(emis, tags, lengths, start, trans, endt, res, marker);
        if (hipGetLastError() != hipSuccess) hm |= 1;
    }
    k_fin<<<1, 64, 0, stream>>>(res, marker, hm, out);
}

// Round 8
// 3791.689 us; speedup vs baseline: 3.6331x; 3.6331x over previous
//
#include <hip/hip_runtime.h>
#include <hip/hip_bf16.h>
#include <stdint.h>

// Problem dims
#define B_  32
#define T_  512
#define E_  256
#define H_  512
#define K_  17
// 4H = 2048

typedef unsigned short us;
typedef __attribute__((ext_vector_type(8))) short short8;
typedef __attribute__((ext_vector_type(4))) float f32x4;

__device__ __forceinline__ float bf2f(unsigned int u16) {
    union { unsigned int i; float f; } v; v.i = u16 << 16; return v.f;
}
__device__ __forceinline__ us f2bf(float f) {
    union { float f; unsigned int i; } v; v.f = f;
    unsigned int b = v.i;
    return (us)((b + 0x7FFFu + ((b >> 16) & 1u)) >> 16);
}
__device__ __forceinline__ float sigf(float x) { return 1.0f / (1.0f + __expf(-x)); }
__device__ __forceinline__ float tanhf_(float x) { return 1.0f - 2.0f / (__expf(2.0f * x) + 1.0f); }

// ---------------------------------------------------------------------------
// Kernel 0: float32 -> bf16 conversion (RNE), 4 elements/thread.
__global__ void k_cvt(const float* __restrict__ src, us* __restrict__ dst, int n4) {
    int i = blockIdx.x * 256 + threadIdx.x;
    if (i < n4) {
        float4 v = ((const float4*)src)[i];
        uint2 p;
        p.x = (uint32_t)f2bf(v.x) | ((uint32_t)f2bf(v.y) << 16);
        p.y = (uint32_t)f2bf(v.z) | ((uint32_t)f2bf(v.w) << 16);
        ((uint2*)dst)[i] = p;
    }
}

// ---------------------------------------------------------------------------
// Kernel 1: sentinel + marker/flags init + gathered token-index table.
// ids2 layout: [dir][t*B + b]
__global__ void k_init(const int* __restrict__ ids, const int* __restrict__ lengths,
                       int* __restrict__ ids2, int* __restrict__ marker,
                       int* __restrict__ flags, float* __restrict__ out) {
    int idx = blockIdx.x * 256 + threadIdx.x;
    if (idx == 0) { *marker = 1; out[0] = -3328.0f; }
    if (idx < 64) flags[idx] = 0;
    if (idx < 2 * B_ * T_) {
        int dir = idx >> 14;           // 16384 per dir
        int r   = idx & 16383;
        int t   = r >> 5;              // t-major, B=32
        int b   = r & 31;
        int l   = lengths[b];
        int tt  = (dir == 0) ? t : ((t < l) ? (l - 1 - t) : t);
        ids2[idx] = ids[b * T_ + tt];
    }
}

// ---------------------------------------------------------------------------
// Kernel 2: xg[dir][t*B+b][jg] = (emb[ids2] @ W_ih^T + bias), permuted layout
// jg = j*4 + g  (torch gates i,f,g,o contiguous per hidden index j).
// M = permuted W rows (2048), N = tokens (16384). 64x64 tiles, K staged 2x128.
__launch_bounds__(256)
__global__ void k_xg(const us* __restrict__ emb,
                     const us* __restrict__ wf, const float* __restrict__ bfv,
                     const us* __restrict__ wb, const float* __restrict__ bbv,
                     const int* __restrict__ ids2, us* __restrict__ xg,
                     int* __restrict__ marker) {
    if (blockIdx.x == 0 && blockIdx.y == 0 && blockIdx.z == 0 && threadIdx.x == 0)
        atomicOr(marker, 2);
    int mt = blockIdx.x, nt = blockIdx.y, dir = blockIdx.z;
    const us* W      = dir ? wb  : wf;
    const float* bias = dir ? bbv : bfv;
    const int* id2 = ids2 + dir * (B_ * T_);
    us* xgd = xg + (size_t)dir * B_ * T_ * 2048;
    int m0 = mt * 64, n0 = nt * 64;
    __shared__ __align__(16) us As[64][136];
    __shared__ __align__(16) us Bs[64][136];
    int tid = threadIdx.x;
    int wv = tid >> 6, lane = tid & 63;
    int lm = lane & 15, lg = lane >> 4;
    f32x4 z = {0.f, 0.f, 0.f, 0.f};
    f32x4 acc[4] = {z, z, z, z};
    for (int half = 0; half < 2; ++half) {
        for (int c = tid; c < 1024; c += 256) {
            int row = c >> 4, cb = c & 15;
            int mg = m0 + row;
            int j = mg >> 2, g = mg & 3;
            *(uint4*)&As[row][cb * 8] =
                *(const uint4*)(W + ((size_t)(g * H_ + j)) * E_ + half * 128 + cb * 8);
            int gi = id2[n0 + row];
            *(uint4*)&Bs[row][cb * 8] =
                *(const uint4*)(emb + (size_t)gi * E_ + half * 128 + cb * 8);
        }
        __syncthreads();
#pragma unroll
        for (int kt = 0; kt < 4; ++kt) {
            short8 a = *(const short8*)&As[wv * 16 + lm][kt * 32 + lg * 8];
#pragma unroll
            for (int n2 = 0; n2 < 4; ++n2) {
                short8 b = *(const short8*)&Bs[n2 * 16 + lm][kt * 32 + lg * 8];
                acc[n2] = __builtin_amdgcn_mfma_f32_16x16x32_bf16(a, b, acc[n2], 0, 0, 0);
            }
        }
        __syncthreads();
    }
    int jgb = m0 + wv * 16 + lg * 4;
    int j = jgb >> 2;
#pragma unroll
    for (int n2 = 0; n2 < 4; ++n2) {
        int token = n0 + n2 * 16 + lm;
        us p[4];
#pragma unroll
        for (int q = 0; q < 4; ++q)
            p[q] = f2bf(acc[n2][q] + bias[q * H_ + j]);
        uint2 pv;
        pv.x = (uint32_t)p[0] | ((uint32_t)p[1] << 16);
        pv.y = (uint32_t)p[2] | ((uint32_t)p[3] << 16);
        *(uint2*)(xgd + (size_t)token * 2048 + jgb) = pv;
    }
}

// ---------------------------------------------------------------------------
// Kernel 3: persistent BiLSTM recurrence. 64 wgs: dir=bid>>5, slice w=bid&31
// (16 hidden j each => 64 permuted gate-rows). W slice LDS-stationary
// (exactly 64 KB, XOR-swizzled). Per step: MFMA G = W.h_{t-1}; lane-local
// cell update (4 gates per lane); h exchange via parity double-buffer:
// plain stores + __threadfence (wbl2, covers the wg's XCD-L2) + device-scope
// atomicAdd counter; readers spin (bounded) then __threadfence (inv).
__launch_bounds__(256)
__global__ void k_lstm(const us* __restrict__ whf, const us* __restrict__ whb,
                       const us* __restrict__ xg,
                       us* __restrict__ h_state, us* __restrict__ h_out,
                       int* __restrict__ flags, int* __restrict__ marker) {
    int bid = blockIdx.x;
    int dir = bid >> 5, w = bid & 31;
    int tid = threadIdx.x;
    if (bid == 0 && tid == 0) atomicOr(marker, 4);
    const us* Wg = dir ? whb : whf;
    __shared__ __align__(16) us Ws[64 * 512];   // 65536 B, swizzled
    for (int c = tid; c < 4096; c += 256) {      // 4096 x 16B chunks
        int row = c >> 6, cb = c & 63;
        int rt = row >> 4, rl = row & 15;
        int jj = rl >> 2, g = rl & 3;
        int srcRow = g * H_ + w * 16 + rt * 4 + jj;
        uint4 v = *(const uint4*)(Wg + (size_t)srcRow * H_ + cb * 8);
        int lb = row * 1024 + ((cb * 16) ^ ((row & 7) << 4));
        *(uint4*)((char*)Ws + lb) = v;
    }
    __syncthreads();
    int wv = tid >> 6, lane = tid & 63;
    int nb = wv & 1, rh = wv >> 1;               // batch-half, row-half
    int lm = lane & 15, lg = lane >> 4;
    int b = nb * 16 + lm;                        // this lane's batch (N index)
    const us* xgd = xg + (size_t)dir * B_ * T_ * 2048;
    us* hs  = h_state + (size_t)dir * (2 * B_ * H_);  // [parity][b][j]
    us* hod = h_out + (size_t)dir * B_ * T_ * H_;
    int* ctr = flags + dir * 32;
    float cc0 = 0.f, cc1 = 0.f;
    bool alive = true;
#pragma unroll 1
    for (int t = 0; t < T_; ++t) {
        f32x4 acc[2];
#pragma unroll
        for (int ti = 0; ti < 2; ++ti) {         // gate init from xg (jg layout)
            int jl = rh * 8 + ti * 4 + lg;
            uint2 v = *(const uint2*)(xgd + ((size_t)(t * 32 + b)) * 2048 + (w * 16 + jl) * 4);
            acc[ti][0] = bf2f(v.x & 0xffff); acc[ti][1] = bf2f(v.x >> 16);
            acc[ti][2] = bf2f(v.y & 0xffff); acc[ti][3] = bf2f(v.y >> 16);
        }
        if (t > 0) {
            if (tid == 0) {
                int target = 32 * t;
                int polls = 0;
                if (alive) {
                    while (__hip_atomic_load(ctr, __ATOMIC_RELAXED, __HIP_MEMORY_SCOPE_AGENT) < target) {
                        __builtin_amdgcn_s_sleep(1);
                        if (++polls > 200000) {           // ~5 ms: fail loud, not hung
                            atomicOr(marker, 32);
                            alive = false;
                            break;
                        }
                    }
                }
                __threadfence();                 // acquire: invalidate local L2
            }
            __syncthreads();
            const us* hp = hs + ((t - 1) & 1) * (B_ * H_) + (size_t)b * H_ + lg * 8;
            uint4 hf[16];
#pragma unroll
            for (int kt = 0; kt < 16; ++kt)
                hf[kt] = *(const uint4*)(hp + kt * 32);
#pragma unroll
            for (int ti = 0; ti < 2; ++ti) {
                int r0 = (rh * 2 + ti) * 16 + lm;
                const char* abase = (const char*)Ws + r0 * 1024;
                int sw = (r0 & 7) << 4;
#pragma unroll
                for (int kt = 0; kt < 16; ++kt) {
                    short8 a = *(const short8*)(abase + ((kt * 64 + lg * 16) ^ sw));
                    acc[ti] = __builtin_amdgcn_mfma_f32_16x16x32_bf16(
                        a, *(const short8*)&hf[kt], acc[ti], 0, 0, 0);
                }
            }
        }
        // cell update (acc[ti][q]: q = gate, torch order i,f,g,o)
        {
            float ci = cc0;
            ci = sigf(acc[0][1]) * ci + sigf(acc[0][0]) * tanhf_(acc[0][2]);
            float h = sigf(acc[0][3]) * tanhf_(ci);
            cc0 = ci;
            us hv = f2bf(h);
            int j = w * 16 + rh * 8 + lg;
            hs[(t & 1) * (B_ * H_) + b * H_ + j] = hv;
            hod[((size_t)b * T_ + t) * H_ + j] = hv;
        }
        {
            float ci = cc1;
            ci = sigf(acc[1][1]) * ci + sigf(acc[1][0]) * tanhf_(acc[1][2]);
            float h = sigf(acc[1][3]) * tanhf_(ci);
            cc1 = ci;
            us hv = f2bf(h);
            int j = w * 16 + rh * 8 + 4 + lg;
            hs[(t & 1) * (B_ * H_) + b * H_ + j] = hv;
            hod[((size_t)b * T_ + t) * H_ + j] = hv;
        }
        __syncthreads();                          // all waves' stores issued+done
        if (tid == 0) {
            __threadfence();                      // release: write back XCD L2
            atomicAdd(ctr, 1);                    // device-scope counter
        }
    }
}

// ---------------------------------------------------------------------------
// Kernel 4: emissions[b*T+t][k] = [hf(b,t), hb(b,rev)] . w_cls[k] + b_cls[k]
__launch_bounds__(256)
__global__ void k_emis(const us* __restrict__ h_out,
                       const us* __restrict__ wcls, const float* __restrict__ bcls,
                       const int* __restrict__ lengths, float* __restrict__ emis,
                       int* __restrict__ marker) {
    if (blockIdx.x == 0 && threadIdx.x == 0) atomicOr(marker, 8);
    __shared__ __align__(8) us Wc[17][1032];
    int tid = threadIdx.x;
    for (int c = tid; c < 17 * 256; c += 256) {
        int row = c >> 8; int c4 = (c & 255) * 4;
        *(uint2*)&Wc[row][c4] = *(const uint2*)(wcls + (size_t)row * 1024 + c4);
    }
    __syncthreads();
    int i = blockIdx.x * 8 + (tid >> 5);
    int k = tid & 31;
    int b = i >> 9, t = i & 511;
    int l = lengths[b];
    int trv = (t < l) ? (l - 1 - t) : t;
    const us* hf = h_out + ((size_t)(0 * B_ + b) * T_ + t) * H_;
    const us* hb = h_out + ((size_t)(1 * B_ + b) * T_ + trv) * H_;
    if (k < K_) {
        float acc = bcls[k];
        for (int e = 0; e < H_; e += 4) {
            uint2 hv = *(const uint2*)(hf + e);
            uint2 wv = *(const uint2*)&Wc[k][e];
            acc = fmaf(bf2f(hv.x & 0xffff), bf2f(wv.x & 0xffff), acc);
            acc = fmaf(bf2f(hv.x >> 16),    bf2f(wv.x >> 16),    acc);
            acc = fmaf(bf2f(hv.y & 0xffff), bf2f(wv.y & 0xffff), acc);
            acc = fmaf(bf2f(hv.y >> 16),    bf2f(wv.y >> 16),    acc);
        }
        for (int e = 0; e < H_; e += 4) {
            uint2 hv = *(const uint2*)(hb + e);
            uint2 wv = *(const uint2*)&Wc[k][512 + e];
            acc = fmaf(bf2f(hv.x & 0xffff), bf2f(wv.x & 0xffff), acc);
            acc = fmaf(bf2f(hv.x >> 16),    bf2f(wv.x >> 16),    acc);
            acc = fmaf(bf2f(hv.y & 0xffff), bf2f(wv.y & 0xffff), acc);
            acc = fmaf(bf2f(hv.y >> 16),    bf2f(wv.y >> 16),    acc);
        }
        emis[(size_t)i * 20 + k] = acc;
    }
}

// ---------------------------------------------------------------------------
// Kernel 5: CRF numerator + forward algorithm per batch (1 wave per batch)
__global__ void k_crf(const float* __restrict__ emis, const int* __restrict__ tags,
                      const int* __restrict__ lengths,
                      const float* __restrict__ start_t, const float* __restrict__ trans_t,
                      const float* __restrict__ end_t, float* __restrict__ res,
                      int* __restrict__ marker) {
    if (blockIdx.x == 0 && threadIdx.x == 0) atomicOr(marker, 16);
    __shared__ float tr[17][18];
    __shared__ float alpha[17];
    int b = blockIdx.x, tid = threadIdx.x;
    for (int i = tid; i < 289; i += 64) tr[i / 17][i % 17] = trans_t[i];
    __syncthreads();
    int l = lengths[b];
    const int* tg = tags + b * T_;
    const float* eb = emis + (size_t)b * T_ * 20;
    float sn = 0.f;
    for (int t = tid; t < T_; t += 64) {
        if (t < l) {
            sn += eb[t * 20 + tg[t]];
            if (t >= 1) sn += tr[tg[t - 1]][tg[t]];
        }
    }
#pragma unroll
    for (int off = 32; off; off >>= 1) sn += __shfl_xor(sn, off, 64);
    float numer = sn + start_t[tg[0]] + end_t[tg[l - 1]];
    int k = (tid < K_) ? tid : 0;
    if (tid < K_) alpha[tid] = start_t[tid] + eb[tid];
    __syncthreads();
    for (int t = 1; t < l; ++t) {
        float av[17];
        float m = -1e30f;
#pragma unroll
        for (int j = 0; j < 17; ++j) { av[j] = alpha[j] + tr[j][k]; m = fmaxf(m, av[j]); }
        float s = 0.f;
#pragma unroll
        for (int j = 0; j < 17; ++j) s += __expf(av[j] - m);
        float nxt = m + __logf(s) + eb[t * 20 + k];
        __syncthreads();
        if (tid < K_) alpha[tid] = nxt;
        __syncthreads();
    }
    float v = (tid < K_) ? (alpha[tid] + end_t[tid]) : -1e30f;
    float m2 = v;
#pragma unroll
    for (int off = 32; off; off >>= 1) m2 = fmaxf(m2, __shfl_xor(m2, off, 64));
    float s2 = __expf(v - m2);
#pragma unroll
    for (int off = 32; off; off >>= 1) s2 += __shfl_xor(s2, off, 64);
    if (tid == 0) res[b] = numer - (m2 + __logf(s2));
}

// ---------------------------------------------------------------------------
// Kernel 6 (LAST): float32 output, negative diagnostic codes:
//   hm!=0 -> -(16384+512*hm) ; dm!=31 -> -(8192+128*(dm&63)) ;
//   NaN in res[b] -> -(4096+b) ; else loss (positive ~1048).
__global__ void k_fin(const float* __restrict__ res, int* __restrict__ marker,
                      int hostmask, float* __restrict__ out) {
    int tid = threadIdx.x;
    if (hostmask != 0) {
        if (tid == 0) out[0] = -(16384.0f + 512.0f * (float)hostmask);
        return;
    }
    int dm = atomicOr(marker, 0);
    if (dm != 31) {
        if (tid == 0) out[0] = -(8192.0f + 128.0f * (float)(dm & 63));
        return;
    }
    float v = (tid < B_) ? res[tid] : 0.f;
    unsigned long long nb = __ballot(v != v);
    if (nb != 0ULL) {
        if (tid == 0) out[0] = -(4096.0f + (float)(__ffsll((long long)nb) - 1));
        return;
    }
#pragma unroll
    for (int off = 32; off; off >>= 1) v += __shfl_xor(v, off, 64);
    if (tid == 0) out[0] = -(v / (float)B_);
}

// ---------------------------------------------------------------------------
extern "C" void kernel_launch(void* const* d_in, const int* in_sizes, int n_in,
                              void* d_out, int out_size, void* d_ws, size_t ws_size,
                              hipStream_t stream) {
    const int* ids      = (const int*)d_in[0];
    const int* lengths  = (const int*)d_in[1];
    const int* tags     = (const int*)d_in[2];
    // d_in[3] = mask (recomputed from lengths)
    const float* emb_f  = (const float*)d_in[4];
    const float* wihf_f = (const float*)d_in[5];
    const float* whhf_f = (const float*)d_in[6];
    const float* bfv    = (const float*)d_in[7];
    const float* wihb_f = (const float*)d_in[8];
    const float* whhb_f = (const float*)d_in[9];
    const float* bbv    = (const float*)d_in[10];
    const float* wcls_f = (const float*)d_in[11];
    const float* bcls   = (const float*)d_in[12];
    const float* start  = (const float*)d_in[13];
    const float* trans  = (const float*)d_in[14];
    const float* endt   = (const float*)d_in[15];
    float* out = (float*)d_out;

    // host-side validation (element counts)
    int hm = 0;
    if (n_in != 16 || out_size != 1) hm |= 8;
    const int exp_sz[16] = {
        16384, 32, 16384, 16384,
        12800000,
        524288, 1048576, 2048,
        524288, 1048576, 2048,
        17408, 17,
        17, 289, 17
    };
    if (!(hm & 8))
        for (int i = 0; i < 16; ++i)
            if (in_sizes[i] != exp_sz[i]) hm |= 2;

    // workspace carve (256B aligned)
    char* w = (char*)d_ws;
    size_t off = 0;
    auto carve = [&](size_t bytes) { void* p = w + off; off += (bytes + 255) & ~(size_t)255; return p; };
    int* ids2    = (int*)carve((size_t)2 * B_ * T_ * 4);
    int* marker  = (int*)carve(256);
    int* flags   = (int*)carve(256);
    float* res   = (float*)carve(256);
    float* emis  = (float*)carve((size_t)B_ * T_ * 20 * 4);
    us* xg       = (us*)carve((size_t)2 * B_ * T_ * 2048 * 2);
    us* h_st     = (us*)carve((size_t)2 * 2 * B_ * H_ * 2);
    us* h_out    = (us*)carve((size_t)2 * B_ * T_ * H_ * 2);
    us* emb_b    = (us*)carve((size_t)12800000 * 2);
    us* wihf_b   = (us*)carve((size_t)524288 * 2);
    us* wihb_b   = (us*)carve((size_t)524288 * 2);
    us* whhf_b   = (us*)carve((size_t)1048576 * 2);
    us* whhb_b   = (us*)carve((size_t)1048576 * 2);
    us* wcls_b   = (us*)carve((size_t)17408 * 2);
    if (off > ws_size) hm |= 4;

    (void)hipGetLastError();
    if ((hm & (2 | 4 | 8)) == 0) {
        k_init<<<(2 * B_ * T_ + 255) / 256, 256, 0, stream>>>(ids, lengths, ids2, marker, flags, out);
        // f32 -> bf16 conversions
        k_cvt<<<(12800000 / 4 + 255) / 256, 256, 0, stream>>>(emb_f,  emb_b,  12800000 / 4);
        k_cvt<<<(524288   / 4 + 255) / 256, 256, 0, stream>>>(wihf_f, wihf_b, 524288 / 4);
        k_cvt<<<(524288   / 4 + 255) / 256, 256, 0, stream>>>(wihb_f, wihb_b, 524288 / 4);
        k_cvt<<<(1048576  / 4 + 255) / 256, 256, 0, stream>>>(whhf_f, whhf_b, 1048576 / 4);
        k_cvt<<<(1048576  / 4 + 255) / 256, 256, 0, stream>>>(whhb_f, whhb_b, 1048576 / 4);
        k_cvt<<<(17408    / 4 + 255) / 256, 256, 0, stream>>>(wcls_f, wcls_b, 17408 / 4);
        k_xg<<<dim3(2048 / 64, B_ * T_ / 64, 2), 256, 0, stream>>>(emb_b, wihf_b, bfv, wihb_b, bbv, ids2, xg, marker);
        k_lstm<<<64, 256, 0, stream>>>(whhf_b, whhb_b, xg, h_st, h_out, flags, marker);
        k_emis<<<B_ * T_ / 8, 256, 0, stream>>>(h_out, wcls_b, bcls, lengths, emis, marker);
        k_crf<<<B_, 64, 0, stream>>>(emis, tags, lengths, start, trans, endt, res, marker);
        if (hipGetLastError() != hipSuccess) hm |= 1;
    }
    k_fin<<<1, 64, 0, stream>>>(res, marker, hm, out);
}

// Round 9
// 3065.915 us; speedup vs baseline: 4.4931x; 1.2367x over previous
//
#include <hip/hip_runtime.h>
#include <hip/hip_bf16.h>
#include <stdint.h>

// Problem dims
#define B_  32
#define T_  512
#define E_  256
#define H_  512
#define K_  17
// 4H = 2048

typedef unsigned short us;
typedef __attribute__((ext_vector_type(8))) short short8;
typedef __attribute__((ext_vector_type(4))) float f32x4;

__device__ __forceinline__ float bf2f(unsigned int u16) {
    union { unsigned int i; float f; } v; v.i = u16 << 16; return v.f;
}
__device__ __forceinline__ us f2bf(float f) {
    union { float f; unsigned int i; } v; v.f = f;
    unsigned int b = v.i;
    return (us)((b + 0x7FFFu + ((b >> 16) & 1u)) >> 16);
}
__device__ __forceinline__ float sigf(float x) { return 1.0f / (1.0f + __expf(-x)); }
__device__ __forceinline__ float tanhf_(float x) { return 1.0f - 2.0f / (__expf(2.0f * x) + 1.0f); }

// ---------------------------------------------------------------------------
// Kernel 0: float32 -> bf16 conversion (RNE), 4 elements/thread.
__global__ void k_cvt(const float* __restrict__ src, us* __restrict__ dst, int n4) {
    int i = blockIdx.x * 256 + threadIdx.x;
    if (i < n4) {
        float4 v = ((const float4*)src)[i];
        uint2 p;
        p.x = (uint32_t)f2bf(v.x) | ((uint32_t)f2bf(v.y) << 16);
        p.y = (uint32_t)f2bf(v.z) | ((uint32_t)f2bf(v.w) << 16);
        ((uint2*)dst)[i] = p;
    }
}

// ---------------------------------------------------------------------------
// Kernel 1: sentinel + marker/slot init + gathered token-index table.
// ids2 layout: [dir][t*B + b]
__global__ void k_init(const int* __restrict__ ids, const int* __restrict__ lengths,
                       int* __restrict__ ids2, int* __restrict__ marker,
                       int* __restrict__ flags, float* __restrict__ out) {
    int idx = blockIdx.x * 256 + threadIdx.x;
    if (idx == 0) { *marker = 1; out[0] = -3328.0f; }
    if (idx < 1024) flags[idx] = 0;             // 2 dirs x 32 slots x 16-int pad
    if (idx < 2 * B_ * T_) {
        int dir = idx >> 14;           // 16384 per dir
        int r   = idx & 16383;
        int t   = r >> 5;              // t-major, B=32
        int b   = r & 31;
        int l   = lengths[b];
        int tt  = (dir == 0) ? t : ((t < l) ? (l - 1 - t) : t);
        ids2[idx] = ids[b * T_ + tt];
    }
}

// ---------------------------------------------------------------------------
// Kernel 2: xg[dir][t*B+b][jg] = (emb[ids2] @ W_ih^T + bias), permuted layout
// jg = j*4 + g  (torch gates i,f,g,o contiguous per hidden index j).
__launch_bounds__(256)
__global__ void k_xg(const us* __restrict__ emb,
                     const us* __restrict__ wf, const float* __restrict__ bfv,
                     const us* __restrict__ wb, const float* __restrict__ bbv,
                     const int* __restrict__ ids2, us* __restrict__ xg,
                     int* __restrict__ marker) {
    if (blockIdx.x == 0 && blockIdx.y == 0 && blockIdx.z == 0 && threadIdx.x == 0)
        atomicOr(marker, 2);
    int mt = blockIdx.x, nt = blockIdx.y, dir = blockIdx.z;
    const us* W      = dir ? wb  : wf;
    const float* bias = dir ? bbv : bfv;
    const int* id2 = ids2 + dir * (B_ * T_);
    us* xgd = xg + (size_t)dir * B_ * T_ * 2048;
    int m0 = mt * 64, n0 = nt * 64;
    __shared__ __align__(16) us As[64][136];
    __shared__ __align__(16) us Bs[64][136];
    int tid = threadIdx.x;
    int wv = tid >> 6, lane = tid & 63;
    int lm = lane & 15, lg = lane >> 4;
    f32x4 z = {0.f, 0.f, 0.f, 0.f};
    f32x4 acc[4] = {z, z, z, z};
    for (int half = 0; half < 2; ++half) {
        for (int c = tid; c < 1024; c += 256) {
            int row = c >> 4, cb = c & 15;
            int mg = m0 + row;
            int j = mg >> 2, g = mg & 3;
            *(uint4*)&As[row][cb * 8] =
                *(const uint4*)(W + ((size_t)(g * H_ + j)) * E_ + half * 128 + cb * 8);
            int gi = id2[n0 + row];
            *(uint4*)&Bs[row][cb * 8] =
                *(const uint4*)(emb + (size_t)gi * E_ + half * 128 + cb * 8);
        }
        __syncthreads();
#pragma unroll
        for (int kt = 0; kt < 4; ++kt) {
            short8 a = *(const short8*)&As[wv * 16 + lm][kt * 32 + lg * 8];
#pragma unroll
            for (int n2 = 0; n2 < 4; ++n2) {
                short8 b = *(const short8*)&Bs[n2 * 16 + lm][kt * 32 + lg * 8];
                acc[n2] = __builtin_amdgcn_mfma_f32_16x16x32_bf16(a, b, acc[n2], 0, 0, 0);
            }
        }
        __syncthreads();
    }
    int jgb = m0 + wv * 16 + lg * 4;
    int j = jgb >> 2;
#pragma unroll
    for (int n2 = 0; n2 < 4; ++n2) {
        int token = n0 + n2 * 16 + lm;
        us p[4];
#pragma unroll
        for (int q = 0; q < 4; ++q)
            p[q] = f2bf(acc[n2][q] + bias[q * H_ + j]);
        uint2 pv;
        pv.x = (uint32_t)p[0] | ((uint32_t)p[1] << 16);
        pv.y = (uint32_t)p[2] | ((uint32_t)p[3] << 16);
        *(uint2*)(xgd + (size_t)token * 2048 + jgb) = pv;
    }
}

// ---------------------------------------------------------------------------
// Kernel 3: persistent BiLSTM recurrence — fence-free coherent exchange.
// 64 wgs: dir=bid>>5, slice w=bid&31 (16 hidden j each). W slice 64 KB LDS
// (XOR-swizzled). Per step: MFMA G = W.h_{t-1} (B-operand = h via u64
// AGENT atomic loads = L2-bypass, always fresh); lane-local cell update;
// h repacked through 1 KB LDS then published with one u32 atomicExch/lane
// (write-through to MALL). Publish: padded per-wg slot (64 B stride) set to
// t+1 AFTER __syncthreads (which drains vmcnt). Readers: wave 0 polls the
// 32 slots in parallel + __all ballot. No __threadfence anywhere: no
// buffer_wbl2 flushes, no buffer_inv invalidations.
__launch_bounds__(256)
__global__ void k_lstm(const us* __restrict__ whf, const us* __restrict__ whb,
                       const us* __restrict__ xg,
                       us* __restrict__ h_state, us* __restrict__ h_out,
                       int* __restrict__ flags, int* __restrict__ marker) {
    int bid = blockIdx.x;
    int dir = bid >> 5, w = bid & 31;
    int tid = threadIdx.x;
    if (bid == 0 && tid == 0) atomicOr(marker, 4);
    const us* Wg = dir ? whb : whf;
    __shared__ __align__(16) us Ws[64 * 512];   // 65536 B, swizzled
    __shared__ __align__(4)  us Hx[32 * 16];    // h repack [b][j_loc], 1 KB
    for (int c = tid; c < 4096; c += 256) {      // 4096 x 16B chunks
        int row = c >> 6, cb = c & 63;
        int rt = row >> 4, rl = row & 15;
        int jj = rl >> 2, g = rl & 3;
        int srcRow = g * H_ + w * 16 + rt * 4 + jj;
        uint4 v = *(const uint4*)(Wg + (size_t)srcRow * H_ + cb * 8);
        int lb = row * 1024 + ((cb * 16) ^ ((row & 7) << 4));
        *(uint4*)((char*)Ws + lb) = v;
    }
    __syncthreads();
    int wv = tid >> 6, lane = tid & 63;
    int nb = wv & 1, rh = wv >> 1;               // batch-half, row-half
    int lm = lane & 15, lg = lane >> 4;
    int b = nb * 16 + lm;                        // this lane's batch (N index)
    const us* xgd = xg + (size_t)dir * B_ * T_ * 2048;
    us* hod = h_out + (size_t)dir * B_ * T_ * H_;
    int* slots = flags + dir * 512;              // 32 slots, stride 16 ints
    const uint64_t* hbase = (const uint64_t*)h_state + (size_t)dir * 8192;
    uint32_t* hw32 = (uint32_t*)h_state + (size_t)dir * 16384;
    float cc0 = 0.f, cc1 = 0.f;
    bool alive = true;
#pragma unroll 1
    for (int t = 0; t < T_; ++t) {
        f32x4 acc[2];
#pragma unroll
        for (int ti = 0; ti < 2; ++ti) {         // gate init from xg (jg layout)
            int jl = rh * 8 + ti * 4 + lg;
            uint2 v = *(const uint2*)(xgd + ((size_t)(t * 32 + b)) * 2048 + (w * 16 + jl) * 4);
            acc[ti][0] = bf2f(v.x & 0xffff); acc[ti][1] = bf2f(v.x >> 16);
            acc[ti][2] = bf2f(v.y & 0xffff); acc[ti][3] = bf2f(v.y >> 16);
        }
        if (t > 0) {
            if (wv == 0) {                       // wave 0: parallel 32-slot poll
                int polls = 0;
                for (;;) {
                    int v = (lane < 32)
                        ? __hip_atomic_load(&slots[lane * 16], __ATOMIC_RELAXED, __HIP_MEMORY_SCOPE_AGENT)
                        : 0x7fffffff;
                    if (__all(v >= t) || !alive) break;
                    __builtin_amdgcn_s_sleep(1);
                    if (++polls > 300000) {      // fail loud, not hung
                        if (lane == 0) atomicOr(marker, 32);
                        alive = false;
                    }
                }
            }
            __syncthreads();
            // coherent h_{t-1} read: 16 kt x 16B via 2x u64 AGENT atomic loads
            const uint64_t* hp = hbase + ((t - 1) & 1) * 4096 + (size_t)b * 128 + lg * 2;
            uint64_t hv[32];
#pragma unroll
            for (int kt = 0; kt < 16; ++kt) {
                hv[2 * kt]     = __hip_atomic_load(hp + kt * 8,     __ATOMIC_RELAXED, __HIP_MEMORY_SCOPE_AGENT);
                hv[2 * kt + 1] = __hip_atomic_load(hp + kt * 8 + 1, __ATOMIC_RELAXED, __HIP_MEMORY_SCOPE_AGENT);
            }
#pragma unroll
            for (int ti = 0; ti < 2; ++ti) {
                int r0 = (rh * 2 + ti) * 16 + lm;
                const char* abase = (const char*)Ws + r0 * 1024;
                int sw = (r0 & 7) << 4;
#pragma unroll
                for (int kt = 0; kt < 16; ++kt) {
                    union { uint64_t u[2]; short8 s; } bu;
                    bu.u[0] = hv[2 * kt]; bu.u[1] = hv[2 * kt + 1];
                    short8 a = *(const short8*)(abase + ((kt * 64 + lg * 16) ^ sw));
                    acc[ti] = __builtin_amdgcn_mfma_f32_16x16x32_bf16(a, bu.s, acc[ti], 0, 0, 0);
                }
            }
        }
        // cell update (acc[ti][q]: q = gate, torch order i,f,g,o)
        {
            float ci = cc0;
            ci = sigf(acc[0][1]) * ci + sigf(acc[0][0]) * tanhf_(acc[0][2]);
            float h = sigf(acc[0][3]) * tanhf_(ci);
            cc0 = ci;
            us hv = f2bf(h);
            int jl = rh * 8 + lg;
            Hx[b * 16 + jl] = hv;
            hod[((size_t)b * T_ + t) * H_ + w * 16 + jl] = hv;
        }
        {
            float ci = cc1;
            ci = sigf(acc[1][1]) * ci + sigf(acc[1][0]) * tanhf_(acc[1][2]);
            float h = sigf(acc[1][3]) * tanhf_(ci);
            cc1 = ci;
            us hv = f2bf(h);
            int jl = rh * 8 + 4 + lg;
            Hx[b * 16 + jl] = hv;
            hod[((size_t)b * T_ + t) * H_ + w * 16 + jl] = hv;
        }
        __syncthreads();                          // Hx complete; parity reads done
        {
            // repack: 256 lanes x u32 -> write-through publish to MALL
            uint32_t v = ((const uint32_t*)Hx)[tid];
            int bb = tid >> 3, jp = tid & 7;      // covers h[bb][w*16 + jp*2 .. +1]
            atomicExch(&hw32[(size_t)(t & 1) * 8192 + (size_t)bb * 256 + w * 8 + jp], v);
        }
        __syncthreads();                          // drains vmcnt: publishes complete
        if (tid == 0) atomicExch(&slots[w * 16], t + 1);
    }
}

// ---------------------------------------------------------------------------
// Kernel 4: emissions[b*T+t][k] = [hf(b,t), hb(b,rev)] . w_cls[k] + b_cls[k]
__launch_bounds__(256)
__global__ void k_emis(const us* __restrict__ h_out,
                       const us* __restrict__ wcls, const float* __restrict__ bcls,
                       const int* __restrict__ lengths, float* __restrict__ emis,
                       int* __restrict__ marker) {
    if (blockIdx.x == 0 && threadIdx.x == 0) atomicOr(marker, 8);
    __shared__ __align__(8) us Wc[17][1032];
    int tid = threadIdx.x;
    for (int c = tid; c < 17 * 256; c += 256) {
        int row = c >> 8; int c4 = (c & 255) * 4;
        *(uint2*)&Wc[row][c4] = *(const uint2*)(wcls + (size_t)row * 1024 + c4);
    }
    __syncthreads();
    int i = blockIdx.x * 8 + (tid >> 5);
    int k = tid & 31;
    int b = i >> 9, t = i & 511;
    int l = lengths[b];
    int trv = (t < l) ? (l - 1 - t) : t;
    const us* hf = h_out + ((size_t)(0 * B_ + b) * T_ + t) * H_;
    const us* hb = h_out + ((size_t)(1 * B_ + b) * T_ + trv) * H_;
    if (k < K_) {
        float acc = bcls[k];
        for (int e = 0; e < H_; e += 4) {
            uint2 hv = *(const uint2*)(hf + e);
            uint2 wv = *(const uint2*)&Wc[k][e];
            acc = fmaf(bf2f(hv.x & 0xffff), bf2f(wv.x & 0xffff), acc);
            acc = fmaf(bf2f(hv.x >> 16),    bf2f(wv.x >> 16),    acc);
            acc = fmaf(bf2f(hv.y & 0xffff), bf2f(wv.y & 0xffff), acc);
            acc = fmaf(bf2f(hv.y >> 16),    bf2f(wv.y >> 16),    acc);
        }
        for (int e = 0; e < H_; e += 4) {
            uint2 hv = *(const uint2*)(hb + e);
            uint2 wv = *(const uint2*)&Wc[k][512 + e];
            acc = fmaf(bf2f(hv.x & 0xffff), bf2f(wv.x & 0xffff), acc);
            acc = fmaf(bf2f(hv.x >> 16),    bf2f(wv.x >> 16),    acc);
            acc = fmaf(bf2f(hv.y & 0xffff), bf2f(wv.y & 0xffff), acc);
            acc = fmaf(bf2f(hv.y >> 16),    bf2f(wv.y >> 16),    acc);
        }
        emis[(size_t)i * 20 + k] = acc;
    }
}

// ---------------------------------------------------------------------------
// Kernel 5: CRF numerator + forward algorithm per batch (1 wave per batch)
__global__ void k_crf(const float* __restrict__ emis, const int* __restrict__ tags,
                      const int* __restrict__ lengths,
                      const float* __restrict__ start_t, const float* __restrict__ trans_t,
                      const float* __restrict__ end_t, float* __restrict__ res,
                      int* __restrict__ marker) {
    if (blockIdx.x == 0 && threadIdx.x == 0) atomicOr(marker, 16);
    __shared__ float tr[17][18];
    __shared__ float alpha[17];
    int b = blockIdx.x, tid = threadIdx.x;
    for (int i = tid; i < 289; i += 64) tr[i / 17][i % 17] = trans_t[i];
    __syncthreads();
    int l = lengths[b];
    const int* tg = tags + b * T_;
    const float* eb = emis + (size_t)b * T_ * 20;
    float sn = 0.f;
    for (int t = tid; t < T_; t += 64) {
        if (t < l) {
            sn += eb[t * 20 + tg[t]];
            if (t >= 1) sn += tr[tg[t - 1]][tg[t]];
        }
    }
#pragma unroll
    for (int off = 32; off; off >>= 1) sn += __shfl_xor(sn, off, 64);
    float numer = sn + start_t[tg[0]] + end_t[tg[l - 1]];
    int k = (tid < K_) ? tid : 0;
    if (tid < K_) alpha[tid] = start_t[tid] + eb[tid];
    __syncthreads();
    for (int t = 1; t < l; ++t) {
        float av[17];
        float m = -1e30f;
#pragma unroll
        for (int j = 0; j < 17; ++j) { av[j] = alpha[j] + tr[j][k]; m = fmaxf(m, av[j]); }
        float s = 0.f;
#pragma unroll
        for (int j = 0; j < 17; ++j) s += __expf(av[j] - m);
        float nxt = m + __logf(s) + eb[t * 20 + k];
        __syncthreads();
        if (tid < K_) alpha[tid] = nxt;
        __syncthreads();
    }
    float v = (tid < K_) ? (alpha[tid] + end_t[tid]) : -1e30f;
    float m2 = v;
#pragma unroll
    for (int off = 32; off; off >>= 1) m2 = fmaxf(m2, __shfl_xor(m2, off, 64));
    float s2 = __expf(v - m2);
#pragma unroll
    for (int off = 32; off; off >>= 1) s2 += __shfl_xor(s2, off, 64);
    if (tid == 0) res[b] = numer - (m2 + __logf(s2));
}

// ---------------------------------------------------------------------------
// Kernel 6 (LAST): float32 output, negative diagnostic codes:
//   hm!=0 -> -(16384+512*hm) ; dm!=31 -> -(8192+128*(dm&63)) ;
//   NaN in res[b] -> -(4096+b) ; else loss (positive ~1048).
__global__ void k_fin(const float* __restrict__ res, int* __restrict__ marker,
                      int hostmask, float* __restrict__ out) {
    int tid = threadIdx.x;
    if (hostmask != 0) {
        if (tid == 0) out[0] = -(16384.0f + 512.0f * (float)hostmask);
        return;
    }
    int dm = atomicOr(marker, 0);
    if (dm != 31) {
        if (tid == 0) out[0] = -(8192.0f + 128.0f * (float)(dm & 63));
        return;
    }
    float v = (tid < B_) ? res[tid] : 0.f;
    unsigned long long nb = __ballot(v != v);
    if (nb != 0ULL) {
        if (tid == 0) out[0] = -(4096.0f + (float)(__ffsll((long long)nb) - 1));
        return;
    }
#pragma unroll
    for (int off = 32; off; off >>= 1) v += __shfl_xor(v, off, 64);
    if (tid == 0) out[0] = -(v / (float)B_);
}

// ---------------------------------------------------------------------------
extern "C" void kernel_launch(void* const* d_in, const int* in_sizes, int n_in,
                              void* d_out, int out_size, void* d_ws, size_t ws_size,
                              hipStream_t stream) {
    const int* ids      = (const int*)d_in[0];
    const int* lengths  = (const int*)d_in[1];
    const int* tags     = (const int*)d_in[2];
    // d_in[3] = mask (recomputed from lengths)
    const float* emb_f  = (const float*)d_in[4];
    const float* wihf_f = (const float*)d_in[5];
    const float* whhf_f = (const float*)d_in[6];
    const float* bfv    = (const float*)d_in[7];
    const float* wihb_f = (const float*)d_in[8];
    const float* whhb_f = (const float*)d_in[9];
    const float* bbv    = (const float*)d_in[10];
    const float* wcls_f = (const float*)d_in[11];
    const float* bcls   = (const float*)d_in[12];
    const float* start  = (const float*)d_in[13];
    const float* trans  = (const float*)d_in[14];
    const float* endt   = (const float*)d_in[15];
    float* out = (float*)d_out;

    // host-side validation (element counts)
    int hm = 0;
    if (n_in != 16 || out_size != 1) hm |= 8;
    const int exp_sz[16] = {
        16384, 32, 16384, 16384,
        12800000,
        524288, 1048576, 2048,
        524288, 1048576, 2048,
        17408, 17,
        17, 289, 17
    };
    if (!(hm & 8))
        for (int i = 0; i < 16; ++i)
            if (in_sizes[i] != exp_sz[i]) hm |= 2;

    // workspace carve (256B aligned)
    char* w = (char*)d_ws;
    size_t off = 0;
    auto carve = [&](size_t bytes) { void* p = w + off; off += (bytes + 255) & ~(size_t)255; return p; };
    int* ids2    = (int*)carve((size_t)2 * B_ * T_ * 4);
    int* marker  = (int*)carve(256);
    int* flags   = (int*)carve(4096);            // 2 dirs x 32 slots x 64 B pad
    float* res   = (float*)carve(256);
    float* emis  = (float*)carve((size_t)B_ * T_ * 20 * 4);
    us* xg       = (us*)carve((size_t)2 * B_ * T_ * 2048 * 2);
    us* h_st     = (us*)carve((size_t)2 * 2 * B_ * H_ * 2);
    us* h_out    = (us*)carve((size_t)2 * B_ * T_ * H_ * 2);
    us* emb_b    = (us*)carve((size_t)12800000 * 2);
    us* wihf_b   = (us*)carve((size_t)524288 * 2);
    us* wihb_b   = (us*)carve((size_t)524288 * 2);
    us* whhf_b   = (us*)carve((size_t)1048576 * 2);
    us* whhb_b   = (us*)carve((size_t)1048576 * 2);
    us* wcls_b   = (us*)carve((size_t)17408 * 2);
    if (off > ws_size) hm |= 4;

    (void)hipGetLastError();
    if ((hm & (2 | 4 | 8)) == 0) {
        k_init<<<(2 * B_ * T_ + 255) / 256, 256, 0, stream>>>(ids, lengths, ids2, marker, flags, out);
        // f32 -> bf16 conversions
        k_cvt<<<(12800000 / 4 + 255) / 256, 256, 0, stream>>>(emb_f,  emb_b,  12800000 / 4);
        k_cvt<<<(524288   / 4 + 255) / 256, 256, 0, stream>>>(wihf_f, wihf_b, 524288 / 4);
        k_cvt<<<(524288   / 4 + 255) / 256, 256, 0, stream>>>(wihb_f, wihb_b, 524288 / 4);
        k_cvt<<<(1048576  / 4 + 255) / 256, 256, 0, stream>>>(whhf_f, whhf_b, 1048576 / 4);
        k_cvt<<<(1048576  / 4 + 255) / 256, 256, 0, stream>>>(whhb_f, whhb_b, 1048576 / 4);
        k_cvt<<<(17408    / 4 + 255) / 256, 256, 0, stream>>>(wcls_f, wcls_b, 17408 / 4);
        k_xg<<<dim3(2048 / 64, B_ * T_ / 64, 2), 256, 0, stream>>>(emb_b, wihf_b, bfv, wihb_b, bbv, ids2, xg, marker);
        k_lstm<<<64, 256, 0, stream>>>(whhf_b, whhb_b, xg, h_st, h_out, flags, marker);
        k_emis<<<B_ * T_ / 8, 256, 0, stream>>>(h_out, wcls_b, bcls, lengths, emis, marker);
        k_crf<<<B_, 64, 0, stream>>>(emis, tags, lengths, start, trans, endt, res, marker);
        if (hipGetLastError() != hipSuccess) hm |= 1;
    }
    k_fin<<<1, 64, 0, stream>>>(res, marker, hm, out);
}